// Round 25
// baseline (119.317 us; speedup 1.0000x reference)
//
#include <hip/hip_runtime.h>

// ---- types ----
typedef __bf16 bf16x8 __attribute__((ext_vector_type(8)));
typedef float  f32x4  __attribute__((ext_vector_type(4)));
typedef float  f32x16 __attribute__((ext_vector_type(16)));
typedef unsigned int uint32x4 __attribute__((ext_vector_type(4)));

__device__ __forceinline__ short f2bf(float f) {
  union { float f; unsigned u; } v; v.f = f;
  unsigned r = v.u + 0x7fffu + ((v.u >> 16) & 1u);
  return (short)(r >> 16);
}

// async global->LDS (16B per lane); LDS dest must be wave-uniform base + lane*16
__device__ __forceinline__ void gl_lds16(const short* g, short* l) {
  __builtin_amdgcn_global_load_lds((const __attribute__((address_space(1))) void*)g,
                                   (__attribute__((address_space(3))) void*)l, 16, 0, 0);
}

// ---- cast x fp32 -> bf16 (vectorized) ----
__global__ __launch_bounds__(256) void cast_x_kernel(const float* __restrict__ in,
                                                     short* __restrict__ out, int n4) {
  int i = blockIdx.x * 256 + threadIdx.x;
  if (i >= n4) return;
  float4 f = reinterpret_cast<const float4*>(in)[i];
  short4 o;
  o.x = f2bf(f.x); o.y = f2bf(f.y); o.z = f2bf(f.z); o.w = f2bf(f.w);
  reinterpret_cast<short4*>(out)[i] = o;
}

// ---- transpose + cast: in[R][Cc] fp32 -> out[Cc][R] bf16 ----
__global__ __launch_bounds__(256) void transpose_cast(const float* __restrict__ in,
                                                      short* __restrict__ out, int R, int Cc) {
  __shared__ short tile[64][65];
  int bx = blockIdx.x * 64;
  int by = blockIdx.y * 64;
  int tx = threadIdx.x & 63, ty = threadIdx.x >> 6;
  #pragma unroll
  for (int i = ty; i < 64; i += 4)
    tile[i][tx] = f2bf(in[(size_t)(by + i) * Cc + bx + tx]);
  __syncthreads();
  #pragma unroll
  for (int i = ty; i < 64; i += 4)
    out[(size_t)(bx + i) * R + by + tx] = tile[tx][i];
}

// ==== swizzled fragment layouts (per bh, 64 tiles x 2048 shorts) ====
// Q/K: (t,d) -> (t>>5)*2048 + (((d>>3)&1)<<10) + (t&31)*32 + ((d>>4)<<3) + (d&7)
// V^T: (d,t) -> (t>>5)*2048 + (((t>>3)&1)<<10) + (d&31)*32
//               + ((((t>>4)&1)+((d>>5)<<1))<<3) + (t&7)

// ---- GEMM1 v8: BM=BN=256, 8 waves, 2-phase dbuf + T2 LDS XOR-swizzle +
//      XCD-chunked mapping ----
__global__ __launch_bounds__(512, 1) void gemm_qkv(const short* __restrict__ A,
                                                   const short* __restrict__ Bt,
                                                   const float* __restrict__ bias,
                                                   short* __restrict__ qo,
                                                   short* __restrict__ ko,
                                                   short* __restrict__ vt) {
  const int K = 1024;
  __shared__ short smem[65536];   // 2 x (A 256x64 | B 256x64); epilogue reuses
  int tid = threadIdx.x;
  int x = blockIdx.x & 7, r = blockIdx.x >> 3;    // 192 blocks: 8 XCD x 24
  int mtile = (x * 2 + (r & 1)) * 256;            // mt in [0,16)
  int ntile = (r >> 1) * 256;                     // nt in [0,12)
  int w = tid >> 6, l = tid & 63;
  int wr = w >> 2, wc = w & 3;     // wave tile: rows [wr*128,+128), cols [wc*64,+64)
  int lr = l & 15, lg = l >> 4;

  f32x4 zero4 = {0.f, 0.f, 0.f, 0.f};
  f32x4 acc[8][4];
  #pragma unroll
  for (int i = 0; i < 8; ++i)
    #pragma unroll
    for (int j = 0; j < 4; ++j) acc[i][j] = zero4;

#define STAGE_QKV(BUF, K0) do {                                                      \
    short* Ab_ = smem + (BUF) * 32768;                                               \
    short* Bb_ = Ab_ + 16384;                                                        \
    _Pragma("unroll")                                                                \
    for (int c = 0; c < 4; ++c) {                                                    \
      int idx = tid + c * 512;                                                       \
      int row = idx >> 3, kc = (idx & 7) ^ (row & 7);   /* pre-swizzled source */    \
      gl_lds16(&A[(size_t)(mtile + row) * K + (K0) + kc * 8], &Ab_[idx * 8]);        \
      gl_lds16(&Bt[(size_t)(ntile + row) * K + (K0) + kc * 8], &Bb_[idx * 8]);       \
    }                                                                                \
  } while (0)

  STAGE_QKV(0, 0);
  __syncthreads();
  int cur = 0;
  for (int it = 0; it < 16; ++it) {
    if (it < 15) STAGE_QKV(cur ^ 1, (it + 1) * 64);   // issue next tile early
    const short* Ab = smem + cur * 32768;
    const short* Bb = Ab + 16384;
    __builtin_amdgcn_s_setprio(1);
    #pragma unroll
    for (int kk = 0; kk < 2; ++kk) {
      bf16x8 af[8], bfr[4];
      #pragma unroll
      for (int i = 0; i < 8; ++i) {
        int rA = wr * 128 + i * 16 + lr;
        af[i] = *reinterpret_cast<const bf16x8*>(&Ab[rA * 64 + (((kk * 4 + lg) ^ (rA & 7)) * 8)]);
      }
      #pragma unroll
      for (int j = 0; j < 4; ++j) {
        int rB = wc * 64 + j * 16 + lr;
        bfr[j] = *reinterpret_cast<const bf16x8*>(&Bb[rB * 64 + (((kk * 4 + lg) ^ (rB & 7)) * 8)]);
      }
      #pragma unroll
      for (int i = 0; i < 8; ++i)
        #pragma unroll
        for (int j = 0; j < 4; ++j)
          acc[i][j] = __builtin_amdgcn_mfma_f32_16x16x32_bf16(af[i], bfr[j], acc[i][j], 0, 0, 0);
    }
    __builtin_amdgcn_s_setprio(0);
    __syncthreads();   // drains this iter's stage AFTER compute
    cur ^= 1;
  }
#undef STAGE_QKV

  // ---- epilogue: bias+scale+cvt -> LDS at final swizzled positions -> coalesced stores
  const int sec = ntile >> 10;   // 0=q 1=k 2=v (uniform: ntile is 256-aligned)
  if (sec == 2) {
    #pragma unroll
    for (int j = 0; j < 4; ++j) {
      int nl = wc * 64 + j * 16 + lr;        // [0,256): spans 4 heads
      int d  = nl & 63;
      float bv = bias[ntile + nl];
      #pragma unroll
      for (int i = 0; i < 8; ++i) {
        int lt0 = wr * 128 + i * 16 + lg * 4; // r spans lt&7 consecutively
        int c2 = (nl >> 6) * 8 + (lt0 >> 5);
        int pos = (((lt0 >> 3) & 1) << 10) + (d & 31) * 32 +
                  ((((lt0 >> 4) & 1) + ((d >> 5) << 1)) << 3) + (lt0 & 7);
        short4 pk;
        pk.x = f2bf(acc[i][j][0] + bv);
        pk.y = f2bf(acc[i][j][1] + bv);
        pk.z = f2bf(acc[i][j][2] + bv);
        pk.w = f2bf(acc[i][j][3] + bv);
        *reinterpret_cast<short4*>(&smem[c2 * 2048 + pos]) = pk;
      }
    }
  } else {
    // q scaled by (1/sqrt(64)) * log2(e) so attention works in exp2 domain
    const float sc = (sec == 0) ? 0.18033688f : 1.0f;
    #pragma unroll
    for (int j = 0; j < 4; ++j) {
      int nl = wc * 64 + j * 16 + lr;
      int d  = nl & 63;
      float bv = bias[ntile + nl];
      int dpart = (((d >> 3) & 1) << 10) + ((d >> 4) << 3) + (d & 7);
      #pragma unroll
      for (int i = 0; i < 8; ++i) {
        #pragma unroll
        for (int r2 = 0; r2 < 4; ++r2) {
          int lt = wr * 128 + i * 16 + lg * 4 + r2;
          int c2 = (nl >> 6) * 8 + (lt >> 5);
          smem[c2 * 2048 + (lt & 31) * 32 + dpart] = f2bf((acc[i][j][r2] + bv) * sc);
        }
      }
    }
  }
  __syncthreads();
  short* dst = (sec == 0) ? qo : ((sec == 1) ? ko : vt);
  int bb  = mtile >> 11;
  int h0  = (ntile & 1023) >> 6;
  int gt0 = (mtile & 2047) >> 5;
  #pragma unroll
  for (int c2 = 0; c2 < 32; ++c2) {
    size_t base = (size_t)(bb * 16 + h0 + (c2 >> 3)) * 131072 +
                  (size_t)(gt0 + (c2 & 7)) * 2048;
    *reinterpret_cast<uint2*>(&dst[base + tid * 4]) =
        *reinterpret_cast<const uint2*>(&smem[c2 * 2048 + tid * 4]);
  }
}

// ---- flash attention v19: LDS-SHARED K/V. Block = 4 consecutive q-tiles
//      {base..base+3}, one per wave; all waves consume the SAME kv tile per
//      phase, staged once into LDS (2-phase dbuf, gl_lds, slot-XOR swizzle).
//      L2 traffic /4; no cross-wave merge (each wave owns its full kv range).
//      Quad-pairing (p, 15-p) -> uniform 68 phases per block. ----
template<int DIAG>
__device__ __forceinline__ void attn_step(const short* __restrict__ Kb,
                                          const short* __restrict__ Vb,
                                          const bf16x8* qf,
                                          f32x16& y0, f32x16& y1,
                                          float& m, float& li,
                                          int lq, int hl, int l) {
  f32x16 s;
  #pragma unroll
  for (int r = 0; r < 16; ++r) s[r] = -m;
  __builtin_amdgcn_s_setprio(1);
  #pragma unroll
  for (int ks = 0; ks < 4; ++ks) {
    bf16x8 kf = *reinterpret_cast<const bf16x8*>(&Kb[l * 32 + ((ks ^ ((l >> 1) & 3)) * 8)]);
    s = __builtin_amdgcn_mfma_f32_32x32x16_bf16(kf, qf[ks], s, 0, 0, 0);
  }
  __builtin_amdgcn_s_setprio(0);
  if (DIAG) {
    #pragma unroll
    for (int r = 0; r < 16; ++r) {
      int kvl = (r & 3) + 8 * (r >> 2) + 4 * hl;
      if (kvl > lq) s[r] = -1e30f;
    }
  }
  // per-lane max (no cross-lane op on common path)
  float t0 = fmaxf(fmaxf(s[0], s[1]), s[2]);
  float t1 = fmaxf(fmaxf(s[3], s[4]), s[5]);
  float t2 = fmaxf(fmaxf(s[6], s[7]), s[8]);
  float t3 = fmaxf(fmaxf(s[9], s[10]), s[11]);
  float t4 = fmaxf(fmaxf(s[12], s[13]), s[14]);
  float pm = fmaxf(fmaxf(fmaxf(t0, t1), t2), fmaxf(fmaxf(t3, t4), s[15]));
  if (!__all(pm <= 8.0f)) {          // rare: tile max grew past threshold
    float pmu = fmaxf(pm, __shfl_xor(pm, 32));   // row-uniform
    float delta = fmaxf(pmu, 0.0f);
    float sc = __builtin_amdgcn_exp2f(-delta);
    m += delta;
    li *= sc;
    #pragma unroll
    for (int r = 0; r < 16; ++r) { y0[r] *= sc; y1[r] *= sc; s[r] -= delta; }
  }
  unsigned u[8];
  float rs = 0.f;
  #pragma unroll
  for (int rq = 0; rq < 4; ++rq) {
    float p0 = __builtin_amdgcn_exp2f(s[4 * rq + 0]);
    float p1 = __builtin_amdgcn_exp2f(s[4 * rq + 1]);
    float p2 = __builtin_amdgcn_exp2f(s[4 * rq + 2]);
    float p3 = __builtin_amdgcn_exp2f(s[4 * rq + 3]);
    rs += (p0 + p1) + (p2 + p3);
    asm("v_cvt_pk_bf16_f32 %0, %1, %2" : "=v"(u[rq * 2 + 0]) : "v"(p0), "v"(p1));
    asm("v_cvt_pk_bf16_f32 %0, %1, %2" : "=v"(u[rq * 2 + 1]) : "v"(p2), "v"(p3));
  }
  li += rs;                           // per-lane partial; cross-half sum at end
  asm volatile("v_permlane32_swap_b32 %0, %1" : "+v"(u[0]), "+v"(u[2]));
  asm volatile("v_permlane32_swap_b32 %0, %1" : "+v"(u[1]), "+v"(u[3]));
  asm volatile("v_permlane32_swap_b32 %0, %1" : "+v"(u[4]), "+v"(u[6]));
  asm volatile("v_permlane32_swap_b32 %0, %1" : "+v"(u[5]), "+v"(u[7]));
  uint32x4 w0 = {u[0], u[1], u[2], u[3]};
  uint32x4 w1 = {u[4], u[5], u[6], u[7]};
  bf16x8 pa0 = __builtin_bit_cast(bf16x8, w0);
  bf16x8 pa1 = __builtin_bit_cast(bf16x8, w1);
  __builtin_amdgcn_s_setprio(1);
  {
    bf16x8 vf0 = *reinterpret_cast<const bf16x8*>(&Vb[l * 32 + ((0 ^ ((l >> 1) & 3)) * 8)]);
    bf16x8 vf1 = *reinterpret_cast<const bf16x8*>(&Vb[l * 32 + ((1 ^ ((l >> 1) & 3)) * 8)]);
    bf16x8 vf2 = *reinterpret_cast<const bf16x8*>(&Vb[l * 32 + ((2 ^ ((l >> 1) & 3)) * 8)]);
    bf16x8 vf3 = *reinterpret_cast<const bf16x8*>(&Vb[l * 32 + ((3 ^ ((l >> 1) & 3)) * 8)]);
    y0 = __builtin_amdgcn_mfma_f32_32x32x16_bf16(vf0, pa0, y0, 0, 0, 0);
    y0 = __builtin_amdgcn_mfma_f32_32x32x16_bf16(vf1, pa1, y0, 0, 0, 0);
    y1 = __builtin_amdgcn_mfma_f32_32x32x16_bf16(vf2, pa0, y1, 0, 0, 0);
    y1 = __builtin_amdgcn_mfma_f32_32x32x16_bf16(vf3, pa1, y1, 0, 0, 0);
  }
  __builtin_amdgcn_s_setprio(0);
}

__global__ __launch_bounds__(256, 2) void attn_kernel(const short* __restrict__ q,
                                                      const short* __restrict__ k,
                                                      const short* __restrict__ vt,
                                                      short* __restrict__ y) {
  __shared__ short Ks[2][2048];   // 2-phase dbuf: one 32-kv K tile (4KB each)
  __shared__ short Vs[2][2048];   // matching V^T tile
  const int bid = blockIdx.x;            // 256 blocks: 8 quad-pairs x 32 bh
  const int p = bid >> 5;                // 0..7
  const int b5 = bid & 31;
  const int bh = (b5 & 7) * 4 + (b5 >> 3); // 4 bh per XCD -> K/V L2-resident
  const int tid = threadIdx.x;
  const int w = tid >> 6, l = tid & 63;
  const int lq = l & 31, hl = l >> 5;
  const short* qb = q + (size_t)bh * 131072;
  const short* kb = k + (size_t)bh * 131072;
  const short* vb = vt + (size_t)bh * 131072;
  const int b_ = bh >> 4, h_ = bh & 15;

  // staging decomposition: thread tid fills LDS linear chunk tid*16B;
  // source chunk pre-permuted so reads at slot (ks ^ ((l>>1)&3)) are bank-minimal
  const int sks = (tid & 3) ^ ((tid >> 3) & 3);
  const int soff = (tid >> 2) * 32 + sks * 8;

#define STAGE_ATT(BUF, TILE) do {                                          \
    gl_lds16(kb + (size_t)(TILE) * 2048 + soff, &Ks[BUF][tid * 8]);        \
    gl_lds16(vb + (size_t)(TILE) * 2048 + soff, &Vs[BUF][tid * 8]);        \
  } while (0)

  #pragma unroll 1
  for (int half = 0; half < 2; ++half) {
    const int base = half ? (60 - 4 * p) : 4 * p;   // quad start
    const int tq = base + w;                        // this wave's q-tile
    const int nt = base + 4;                        // phases: tiles 0..base+3

    // Q fragments (own q-tile): one coalesced 64B read per lane
    bf16x8 qf[4];
    {
      const short* qp = qb + (size_t)tq * 2048 + l * 32;
      #pragma unroll
      for (int ks = 0; ks < 4; ++ks)
        qf[ks] = *reinterpret_cast<const bf16x8*>(qp + ks * 8);
    }

    f32x16 y0, y1;
    #pragma unroll
    for (int r = 0; r < 16; ++r) { y0[r] = 0.f; y1[r] = 0.f; }
    float m = 0.f, li = 0.f;

    STAGE_ATT(0, 0);
    __syncthreads();
    int buf = 0;
    for (int it = 0; it < nt; ++it) {
      if (it + 1 < nt) STAGE_ATT(buf ^ 1, it + 1);
      if (it < tq)
        attn_step<0>(&Ks[buf][0], &Vs[buf][0], qf, y0, y1, m, li, lq, hl, l);
      else if (it == tq)
        attn_step<1>(&Ks[buf][0], &Vs[buf][0], qf, y0, y1, m, li, lq, hl, l);
      __syncthreads();   // all reads done + staged tile ready
      buf ^= 1;
    }
    // complete the per-row sum across lane halves
    li += __shfl_xor(li, 32);

    // per-wave epilogue (no merge)
    float inv = 1.0f / li;
    short* yrow = &y[(size_t)(b_ * 2048 + 32 * tq + lq) * 1024 + h_ * 64];
    #pragma unroll
    for (int dt = 0; dt < 2; ++dt) {
      const f32x16& yy = dt ? y1 : y0;
      #pragma unroll
      for (int rq = 0; rq < 4; ++rq) {
        int d0 = dt * 32 + 8 * rq + 4 * hl;
        uint2 pk;
        pk.x = (unsigned)(unsigned short)f2bf(yy[4 * rq + 0] * inv) |
               ((unsigned)(unsigned short)f2bf(yy[4 * rq + 1] * inv) << 16);
        pk.y = (unsigned)(unsigned short)f2bf(yy[4 * rq + 2] * inv) |
               ((unsigned)(unsigned short)f2bf(yy[4 * rq + 3] * inv) << 16);
        *reinterpret_cast<uint2*>(yrow + d0) = pk;
      }
    }
  }
#undef STAGE_ATT
}

// ---- GEMM3 v5: BM=128 x BN=64, 2-phase dbuf + XCD swizzle + T2 LDS swizzle ----
__global__ __launch_bounds__(256, 3) void gemm_proj(const short* __restrict__ A,
                                                    const short* __restrict__ Bt,
                                                    const float* __restrict__ bias,
                                                    float* __restrict__ out) {
  const int K = 1024;
  __shared__ short smem[24576];   // 2 x (A 8192 | B 4096)
  int tid = threadIdx.x;
  int x = blockIdx.x & 7, r = blockIdx.x >> 3;  // r in [0,64)
  int ntile = (x * 2 + (r & 1)) * 64, mtile = (r >> 1) * 128;
  int w = tid >> 6, l = tid & 63;
  int lr = l & 15, lg = l >> 4;

  f32x4 zero4 = {0.f, 0.f, 0.f, 0.f};
  f32x4 acc[2][4];
  #pragma unroll
  for (int i = 0; i < 2; ++i)
    #pragma unroll
    for (int j = 0; j < 4; ++j) acc[i][j] = zero4;

#define STAGE_PRJ(BUF, K0) do {                                                      \
    short* Ab_ = smem + (BUF) * 12288;                                               \
    short* Bb_ = Ab_ + 8192;                                                         \
    _Pragma("unroll")                                                                \
    for (int c = 0; c < 4; ++c) {                                                    \
      int idx = tid + c * 256;                                                       \
      int row = idx >> 3, kc = (idx & 7) ^ (row & 7);                                \
      gl_lds16(&A[(size_t)(mtile + row) * K + (K0) + kc * 8], &Ab_[idx * 8]);        \
    }                                                                                \
    _Pragma("unroll")                                                                \
    for (int c = 0; c < 2; ++c) {                                                    \
      int idx = tid + c * 256;                                                       \
      int row = idx >> 3, kc = (idx & 7) ^ (row & 7);                                \
      gl_lds16(&Bt[(size_t)(ntile + row) * K + (K0) + kc * 8], &Bb_[idx * 8]);       \
    }                                                                                \
  } while (0)

  STAGE_PRJ(0, 0);
  __syncthreads();
  int cur = 0;
  for (int it = 0; it < 16; ++it) {
    if (it < 15) STAGE_PRJ(cur ^ 1, (it + 1) * 64);
    const short* Ab = smem + cur * 12288;
    const short* Bb = Ab + 8192;
    __builtin_amdgcn_s_setprio(1);
    #pragma unroll
    for (int kk = 0; kk < 2; ++kk) {
      bf16x8 af[2], bfr[4];
      #pragma unroll
      for (int i = 0; i < 2; ++i) {
        int rA = w * 32 + i * 16 + lr;
        af[i] = *reinterpret_cast<const bf16x8*>(&Ab[rA * 64 + (((kk * 4 + lg) ^ (rA & 7)) * 8)]);
      }
      #pragma unroll
      for (int j = 0; j < 4; ++j) {
        int rB = j * 16 + lr;
        bfr[j] = *reinterpret_cast<const bf16x8*>(&Bb[rB * 64 + (((kk * 4 + lg) ^ (rB & 7)) * 8)]);
      }
      #pragma unroll
      for (int i = 0; i < 2; ++i)
        #pragma unroll
        for (int j = 0; j < 4; ++j)
          acc[i][j] = __builtin_amdgcn_mfma_f32_16x16x32_bf16(af[i], bfr[j], acc[i][j], 0, 0, 0);
    }
    __builtin_amdgcn_s_setprio(0);
    __syncthreads();
    cur ^= 1;
  }
#undef STAGE_PRJ

  #pragma unroll
  for (int j = 0; j < 4; ++j) {
    int n = ntile + j * 16 + lr;
    float bv = bias[n];
    #pragma unroll
    for (int i = 0; i < 2; ++i) {
      #pragma unroll
      for (int r2 = 0; r2 < 4; ++r2) {
        int m = mtile + w * 32 + i * 16 + lg * 4 + r2;
        out[(size_t)m * 1024 + n] = acc[i][j][r2] + bv;
      }
    }
  }
}

extern "C" void kernel_launch(void* const* d_in, const int* in_sizes, int n_in,
                              void* d_out, int out_size, void* d_ws, size_t ws_size,
                              hipStream_t stream) {
  const float* x     = (const float*)d_in[0];
  const float* Wqkv  = (const float*)d_in[1];
  const float* bqkv  = (const float*)d_in[2];
  const float* Wproj = (const float*)d_in[3];
  const float* bproj = (const float*)d_in[4];
  float* out = (float*)d_out;

  const size_t M4 = 4096ull * 1024ull;
  short* ws = (short*)d_ws;
  short* x_bf    = ws;
  short* wqkv_t  = ws + M4;
  short* wproj_t = ws + M4 + 3ull * 1024 * 1024;
  short* qb      = wproj_t + 1024ull * 1024;
  short* kb      = qb + M4;
  short* vtb     = kb + M4;     // fragment-swizzled V^T
  short* yb      = x_bf;        // alias: x_bf dead after gemm_qkv

  cast_x_kernel<<<4096, 256, 0, stream>>>(x, x_bf, (int)(M4 / 4));
  transpose_cast<<<dim3(48, 16), 256, 0, stream>>>(Wqkv, wqkv_t, 1024, 3072);
  transpose_cast<<<dim3(16, 16), 256, 0, stream>>>(Wproj, wproj_t, 1024, 1024);
  gemm_qkv<<<192, 512, 0, stream>>>(x_bf, wqkv_t, bqkv, qb, kb, vtb);
  attn_kernel<<<256, 256, 0, stream>>>(qb, kb, vtb, yb);
  gemm_proj<<<512, 256, 0, stream>>>(yb, wproj_t, bproj, out);
}

// Round 26
// 112.196 us; speedup vs baseline: 1.0635x; 1.0635x over previous
//
#include <hip/hip_runtime.h>

// ---- types ----
typedef __bf16 bf16x8 __attribute__((ext_vector_type(8)));
typedef float  f32x4  __attribute__((ext_vector_type(4)));
typedef float  f32x16 __attribute__((ext_vector_type(16)));
typedef unsigned int uint32x4 __attribute__((ext_vector_type(4)));

__device__ __forceinline__ short f2bf(float f) {
  union { float f; unsigned u; } v; v.f = f;
  unsigned r = v.u + 0x7fffu + ((v.u >> 16) & 1u);
  return (short)(r >> 16);
}

// async global->LDS (16B per lane); LDS dest must be wave-uniform base + lane*16
__device__ __forceinline__ void gl_lds16(const short* g, short* l) {
  __builtin_amdgcn_global_load_lds((const __attribute__((address_space(1))) void*)g,
                                   (__attribute__((address_space(3))) void*)l, 16, 0, 0);
}

// ---- cast x fp32 -> bf16 (vectorized) ----
__global__ __launch_bounds__(256) void cast_x_kernel(const float* __restrict__ in,
                                                     short* __restrict__ out, int n4) {
  int i = blockIdx.x * 256 + threadIdx.x;
  if (i >= n4) return;
  float4 f = reinterpret_cast<const float4*>(in)[i];
  short4 o;
  o.x = f2bf(f.x); o.y = f2bf(f.y); o.z = f2bf(f.z); o.w = f2bf(f.w);
  reinterpret_cast<short4*>(out)[i] = o;
}

// ---- transpose + cast: in[R][Cc] fp32 -> out[Cc][R] bf16 ----
__global__ __launch_bounds__(256) void transpose_cast(const float* __restrict__ in,
                                                      short* __restrict__ out, int R, int Cc) {
  __shared__ short tile[64][65];
  int bx = blockIdx.x * 64;
  int by = blockIdx.y * 64;
  int tx = threadIdx.x & 63, ty = threadIdx.x >> 6;
  #pragma unroll
  for (int i = ty; i < 64; i += 4)
    tile[i][tx] = f2bf(in[(size_t)(by + i) * Cc + bx + tx]);
  __syncthreads();
  #pragma unroll
  for (int i = ty; i < 64; i += 4)
    out[(size_t)(bx + i) * R + by + tx] = tile[tx][i];
}

// ==== swizzled fragment layouts (per bh, 64 tiles x 2048 shorts) ====
// Q/K: (t,d) -> (t>>5)*2048 + (((d>>3)&1)<<10) + (t&31)*32 + ((d>>4)<<3) + (d&7)
// V^T: (d,t) -> (t>>5)*2048 + (((t>>3)&1)<<10) + (d&31)*32
//               + ((((t>>4)&1)+((d>>5)<<1))<<3) + (t&7)

// ---- GEMM1 v9: BM=BN=256, 8 waves, T2 LDS XOR-swizzle, XCD-chunked mapping,
//      COUNTED-vmcnt 2-buffer pipeline (T4): raw s_barrier + s_waitcnt vmcnt(8)
//      -> the freshly-issued stage stays in flight across the barrier ----
__global__ __launch_bounds__(512, 1) void gemm_qkv(const short* __restrict__ A,
                                                   const short* __restrict__ Bt,
                                                   const float* __restrict__ bias,
                                                   short* __restrict__ qo,
                                                   short* __restrict__ ko,
                                                   short* __restrict__ vt) {
  const int K = 1024;
  __shared__ short smem[65536];   // 2 x (A 256x64 | B 256x64); epilogue reuses
  int tid = threadIdx.x;
  int x = blockIdx.x & 7, r = blockIdx.x >> 3;    // 192 blocks: 8 XCD x 24
  int mtile = (x * 2 + (r & 1)) * 256;            // mt in [0,16)
  int ntile = (r >> 1) * 256;                     // nt in [0,12)
  int w = tid >> 6, l = tid & 63;
  int wr = w >> 2, wc = w & 3;     // wave tile: rows [wr*128,+128), cols [wc*64,+64)
  int lr = l & 15, lg = l >> 4;

  f32x4 zero4 = {0.f, 0.f, 0.f, 0.f};
  f32x4 acc[8][4];
  #pragma unroll
  for (int i = 0; i < 8; ++i)
    #pragma unroll
    for (int j = 0; j < 4; ++j) acc[i][j] = zero4;

#define STAGE_QKV(BUF, K0) do {                                                      \
    short* Ab_ = smem + (BUF) * 32768;                                               \
    short* Bb_ = Ab_ + 16384;                                                        \
    _Pragma("unroll")                                                                \
    for (int c = 0; c < 4; ++c) {                                                    \
      int idx = tid + c * 512;                                                       \
      int row = idx >> 3, kc = (idx & 7) ^ (row & 7);   /* pre-swizzled source */    \
      gl_lds16(&A[(size_t)(mtile + row) * K + (K0) + kc * 8], &Ab_[idx * 8]);        \
      gl_lds16(&Bt[(size_t)(ntile + row) * K + (K0) + kc * 8], &Bb_[idx * 8]);       \
    }                                                                                \
  } while (0)

  STAGE_QKV(0, 0);
  STAGE_QKV(1, 64);                 // 16 loads/thread in flight
  for (int it = 0; it < 16; ++it) {
    if (it < 15) asm volatile("s_waitcnt vmcnt(8)" ::: "memory");   // oldest stage landed
    else         asm volatile("s_waitcnt vmcnt(0)" ::: "memory");   // final stage
    __builtin_amdgcn_s_barrier();   // all waves see buffer (it&1) ready
    asm volatile("" ::: "memory");
    const short* Ab = smem + (it & 1) * 32768;
    const short* Bb = Ab + 16384;
    __builtin_amdgcn_s_setprio(1);
    #pragma unroll
    for (int kk = 0; kk < 2; ++kk) {
      bf16x8 af[8], bfr[4];
      #pragma unroll
      for (int i = 0; i < 8; ++i) {
        int rA = wr * 128 + i * 16 + lr;
        af[i] = *reinterpret_cast<const bf16x8*>(&Ab[rA * 64 + (((kk * 4 + lg) ^ (rA & 7)) * 8)]);
      }
      #pragma unroll
      for (int j = 0; j < 4; ++j) {
        int rB = wc * 64 + j * 16 + lr;
        bfr[j] = *reinterpret_cast<const bf16x8*>(&Bb[rB * 64 + (((kk * 4 + lg) ^ (rB & 7)) * 8)]);
      }
      #pragma unroll
      for (int i = 0; i < 8; ++i)
        #pragma unroll
        for (int j = 0; j < 4; ++j)
          acc[i][j] = __builtin_amdgcn_mfma_f32_16x16x32_bf16(af[i], bfr[j], acc[i][j], 0, 0, 0);
    }
    __builtin_amdgcn_s_setprio(0);
    __builtin_amdgcn_s_barrier();   // all waves done reading buffer (it&1)
    asm volatile("" ::: "memory");
    if (it + 2 < 16) STAGE_QKV(it & 1, (it + 2) * 64);  // overwrite just-read buffer
  }
#undef STAGE_QKV
  __syncthreads();   // drain everything before epilogue LDS reuse

  // ---- epilogue: bias+scale+cvt -> LDS at final swizzled positions -> coalesced stores
  const int sec = ntile >> 10;   // 0=q 1=k 2=v (uniform: ntile is 256-aligned)
  if (sec == 2) {
    #pragma unroll
    for (int j = 0; j < 4; ++j) {
      int nl = wc * 64 + j * 16 + lr;        // [0,256): spans 4 heads
      int d  = nl & 63;
      float bv = bias[ntile + nl];
      #pragma unroll
      for (int i = 0; i < 8; ++i) {
        int lt0 = wr * 128 + i * 16 + lg * 4; // r spans lt&7 consecutively
        int c2 = (nl >> 6) * 8 + (lt0 >> 5);
        int pos = (((lt0 >> 3) & 1) << 10) + (d & 31) * 32 +
                  ((((lt0 >> 4) & 1) + ((d >> 5) << 1)) << 3) + (lt0 & 7);
        short4 pk;
        pk.x = f2bf(acc[i][j][0] + bv);
        pk.y = f2bf(acc[i][j][1] + bv);
        pk.z = f2bf(acc[i][j][2] + bv);
        pk.w = f2bf(acc[i][j][3] + bv);
        *reinterpret_cast<short4*>(&smem[c2 * 2048 + pos]) = pk;
      }
    }
  } else {
    // q scaled by (1/sqrt(64)) * log2(e) so attention works in exp2 domain
    const float sc = (sec == 0) ? 0.18033688f : 1.0f;
    #pragma unroll
    for (int j = 0; j < 4; ++j) {
      int nl = wc * 64 + j * 16 + lr;
      int d  = nl & 63;
      float bv = bias[ntile + nl];
      int dpart = (((d >> 3) & 1) << 10) + ((d >> 4) << 3) + (d & 7);
      #pragma unroll
      for (int i = 0; i < 8; ++i) {
        #pragma unroll
        for (int r2 = 0; r2 < 4; ++r2) {
          int lt = wr * 128 + i * 16 + lg * 4 + r2;
          int c2 = (nl >> 6) * 8 + (lt >> 5);
          smem[c2 * 2048 + (lt & 31) * 32 + dpart] = f2bf((acc[i][j][r2] + bv) * sc);
        }
      }
    }
  }
  __syncthreads();
  short* dst = (sec == 0) ? qo : ((sec == 1) ? ko : vt);
  int bb  = mtile >> 11;
  int h0  = (ntile & 1023) >> 6;
  int gt0 = (mtile & 2047) >> 5;
  #pragma unroll
  for (int c2 = 0; c2 < 32; ++c2) {
    size_t base = (size_t)(bb * 16 + h0 + (c2 >> 3)) * 131072 +
                  (size_t)(gt0 + (c2 & 7)) * 2048;
    *reinterpret_cast<uint2*>(&dst[base + tid * 4]) =
        *reinterpret_cast<const uint2*>(&smem[c2 * 2048 + tid * 4]);
  }
}

// ---- flash attention v18 (r24 best, reverted from r25): paired q-tiles,
//      chain-shortened softmax, C-in=-m init, kv-split + two-pass merge ----
template<int DIAG>
__device__ __forceinline__ void attn_step(const short* __restrict__ kp,
                                          const short* __restrict__ vp,
                                          const bf16x8* qf,
                                          f32x16& y0, f32x16& y1,
                                          float& m, float& li,
                                          int lq, int hl) {
  f32x16 s;
  #pragma unroll
  for (int r = 0; r < 16; ++r) s[r] = -m;
  __builtin_amdgcn_s_setprio(1);
  #pragma unroll
  for (int ks = 0; ks < 4; ++ks) {
    bf16x8 kf = *reinterpret_cast<const bf16x8*>(kp + ks * 8);
    s = __builtin_amdgcn_mfma_f32_32x32x16_bf16(kf, qf[ks], s, 0, 0, 0);
  }
  __builtin_amdgcn_s_setprio(0);
  if (DIAG) {
    #pragma unroll
    for (int r = 0; r < 16; ++r) {
      int kvl = (r & 3) + 8 * (r >> 2) + 4 * hl;
      if (kvl > lq) s[r] = -1e30f;
    }
  }
  float t0 = fmaxf(fmaxf(s[0], s[1]), s[2]);
  float t1 = fmaxf(fmaxf(s[3], s[4]), s[5]);
  float t2 = fmaxf(fmaxf(s[6], s[7]), s[8]);
  float t3 = fmaxf(fmaxf(s[9], s[10]), s[11]);
  float t4 = fmaxf(fmaxf(s[12], s[13]), s[14]);
  float pm = fmaxf(fmaxf(fmaxf(t0, t1), t2), fmaxf(fmaxf(t3, t4), s[15]));
  if (!__all(pm <= 8.0f)) {          // rare: tile max grew past threshold
    float pmu = fmaxf(pm, __shfl_xor(pm, 32));   // row-uniform (shfl only here)
    float delta = fmaxf(pmu, 0.0f);
    float sc = __builtin_amdgcn_exp2f(-delta);
    m += delta;
    li *= sc;
    #pragma unroll
    for (int r = 0; r < 16; ++r) { y0[r] *= sc; y1[r] *= sc; s[r] -= delta; }
  }
  unsigned u[8];
  float rs = 0.f;
  #pragma unroll
  for (int rq = 0; rq < 4; ++rq) {
    float p0 = __builtin_amdgcn_exp2f(s[4 * rq + 0]);
    float p1 = __builtin_amdgcn_exp2f(s[4 * rq + 1]);
    float p2 = __builtin_amdgcn_exp2f(s[4 * rq + 2]);
    float p3 = __builtin_amdgcn_exp2f(s[4 * rq + 3]);
    rs += (p0 + p1) + (p2 + p3);
    asm("v_cvt_pk_bf16_f32 %0, %1, %2" : "=v"(u[rq * 2 + 0]) : "v"(p0), "v"(p1));
    asm("v_cvt_pk_bf16_f32 %0, %1, %2" : "=v"(u[rq * 2 + 1]) : "v"(p2), "v"(p3));
  }
  li += rs;                           // per-lane partial; cross-half sum deferred
  asm volatile("v_permlane32_swap_b32 %0, %1" : "+v"(u[0]), "+v"(u[2]));
  asm volatile("v_permlane32_swap_b32 %0, %1" : "+v"(u[1]), "+v"(u[3]));
  asm volatile("v_permlane32_swap_b32 %0, %1" : "+v"(u[4]), "+v"(u[6]));
  asm volatile("v_permlane32_swap_b32 %0, %1" : "+v"(u[5]), "+v"(u[7]));
  uint32x4 w0 = {u[0], u[1], u[2], u[3]};
  uint32x4 w1 = {u[4], u[5], u[6], u[7]};
  bf16x8 pa0 = __builtin_bit_cast(bf16x8, w0);
  bf16x8 pa1 = __builtin_bit_cast(bf16x8, w1);
  __builtin_amdgcn_s_setprio(1);
  {
    bf16x8 vf00 = *reinterpret_cast<const bf16x8*>(vp);
    bf16x8 vf01 = *reinterpret_cast<const bf16x8*>(vp + 8);
    bf16x8 vf10 = *reinterpret_cast<const bf16x8*>(vp + 16);
    bf16x8 vf11 = *reinterpret_cast<const bf16x8*>(vp + 24);
    y0 = __builtin_amdgcn_mfma_f32_32x32x16_bf16(vf00, pa0, y0, 0, 0, 0);
    y0 = __builtin_amdgcn_mfma_f32_32x32x16_bf16(vf01, pa1, y0, 0, 0, 0);
    y1 = __builtin_amdgcn_mfma_f32_32x32x16_bf16(vf10, pa0, y1, 0, 0, 0);
    y1 = __builtin_amdgcn_mfma_f32_32x32x16_bf16(vf11, pa1, y1, 0, 0, 0);
  }
  __builtin_amdgcn_s_setprio(0);
}

__global__ __launch_bounds__(256, 4) void attn_kernel(const short* __restrict__ q,
                                                      const short* __restrict__ k,
                                                      const short* __restrict__ vt,
                                                      short* __restrict__ y) {
  __shared__ float partL[3][4][64][4];   // 12 KB, reused across passes/halves
  __shared__ float stm[4][32], stl[4][32];
  const int bid = blockIdx.x;            // 1024 blocks: 32 pairs x 32 bh
  const int p = bid >> 5;                // pair index 0..31
  const int b5 = bid & 31;
  const int bh = (b5 & 7) * 4 + (b5 >> 3); // group each bh's blocks on one XCD
  const int tid = threadIdx.x;
  const int w = tid >> 6;                // wave: kv-split index 0..3
  const int l = tid & 63;
  const int lq = l & 31, hl = l >> 5;
  const short* qb = q + (size_t)bh * 131072;
  const short* kb = k + (size_t)bh * 131072;
  const short* vb = vt + (size_t)bh * 131072;
  const int b_ = bh >> 4, h_ = bh & 15;

  #pragma unroll 1
  for (int half = 0; half < 2; ++half) {
    const int t = half ? p : (63 - p);   // q-tile for this pass; total work 65 tiles

    // Q fragments: swizzled -> one coalesced 64B read per lane
    bf16x8 qf[4];
    {
      const short* qp = qb + (size_t)t * 2048 + l * 32;
      #pragma unroll
      for (int ks = 0; ks < 4; ++ks)
        qf[ks] = *reinterpret_cast<const bf16x8*>(qp + ks * 8);
    }

    f32x16 y0, y1;
    #pragma unroll
    for (int r = 0; r < 16; ++r) { y0[r] = 0.f; y1[r] = 0.f; }
    float m = 0.f, li = 0.f;   // m init 0 (defer-max in relative/log2 domain)

    // wave w handles kv tiles {w, w+4, ...} < t, plus diag tile t if t&3==w
    const short* kp = kb + (size_t)w * 2048 + l * 32;
    const short* vp = vb + (size_t)w * 2048 + l * 32;
    for (int it = w; it < t; it += 4) {
      attn_step<0>(kp, vp, qf, y0, y1, m, li, lq, hl);
      kp += 4 * 2048;
      vp += 4 * 2048;
    }
    if ((t & 3) == w) {
      const short* kpd = kb + (size_t)t * 2048 + l * 32;
      const short* vpd = vb + (size_t)t * 2048 + l * 32;
      attn_step<1>(kpd, vpd, qf, y0, y1, m, li, lq, hl);
    }
    // complete the deferred cross-half li sum (per q-row)
    li += __shfl_xor(li, 32);

    // ---- merge the 4 wave-partials (two passes over a half-size buffer) ----
    if (hl == 0) { stm[w][lq] = m; stl[w][lq] = li; }
    __syncthreads();
    float m0 = stm[0][lq], m1 = stm[1][lq], m2 = stm[2][lq], m3 = stm[3][lq];
    float M = fmaxf(fmaxf(m0, m1), fmaxf(m2, m3));
    float L = stl[0][lq] * __builtin_amdgcn_exp2f(m0 - M) +
              stl[1][lq] * __builtin_amdgcn_exp2f(m1 - M) +
              stl[2][lq] * __builtin_amdgcn_exp2f(m2 - M) +
              stl[3][lq] * __builtin_amdgcn_exp2f(m3 - M);
    float sc = __builtin_amdgcn_exp2f(m - M);
    #pragma unroll
    for (int r = 0; r < 16; ++r) { y0[r] *= sc; y1[r] *= sc; }

    // pass 0: merge y0
    if (w > 0) {
      #pragma unroll
      for (int c = 0; c < 4; ++c) {
        f32x4 v0s = {y0[4 * c + 0], y0[4 * c + 1], y0[4 * c + 2], y0[4 * c + 3]};
        *reinterpret_cast<f32x4*>(&partL[w - 1][c][l][0]) = v0s;
      }
    }
    __syncthreads();
    if (w == 0) {
      #pragma unroll
      for (int o = 0; o < 3; ++o)
        #pragma unroll
        for (int c = 0; c < 4; ++c) {
          f32x4 v0s = *reinterpret_cast<const f32x4*>(&partL[o][c][l][0]);
          #pragma unroll
          for (int r = 0; r < 4; ++r) y0[4 * c + r] += v0s[r];
        }
    }
    __syncthreads();
    // pass 1: merge y1 (buffer reused)
    if (w > 0) {
      #pragma unroll
      for (int c = 0; c < 4; ++c) {
        f32x4 v1s = {y1[4 * c + 0], y1[4 * c + 1], y1[4 * c + 2], y1[4 * c + 3]};
        *reinterpret_cast<f32x4*>(&partL[w - 1][c][l][0]) = v1s;
      }
    }
    __syncthreads();
    if (w == 0) {
      #pragma unroll
      for (int o = 0; o < 3; ++o)
        #pragma unroll
        for (int c = 0; c < 4; ++c) {
          f32x4 v1s = *reinterpret_cast<const f32x4*>(&partL[o][c][l][0]);
          #pragma unroll
          for (int r = 0; r < 4; ++r) y1[4 * c + r] += v1s[r];
        }
      float inv = 1.0f / L;
      short* yrow = &y[(size_t)(b_ * 2048 + 32 * t + lq) * 1024 + h_ * 64];
      #pragma unroll
      for (int dt = 0; dt < 2; ++dt) {
        const f32x16& yy = dt ? y1 : y0;
        #pragma unroll
        for (int rq = 0; rq < 4; ++rq) {
          int d0 = dt * 32 + 8 * rq + 4 * hl;
          uint2 pk;
          pk.x = (unsigned)(unsigned short)f2bf(yy[4 * rq + 0] * inv) |
                 ((unsigned)(unsigned short)f2bf(yy[4 * rq + 1] * inv) << 16);
          pk.y = (unsigned)(unsigned short)f2bf(yy[4 * rq + 2] * inv) |
                 ((unsigned)(unsigned short)f2bf(yy[4 * rq + 3] * inv) << 16);
          *reinterpret_cast<uint2*>(yrow + d0) = pk;
        }
      }
    }
    __syncthreads();   // protect stm/partL reuse by next half
  }
}

// ---- GEMM3 v5: BM=128 x BN=64, 2-phase dbuf + XCD swizzle + T2 LDS swizzle ----
__global__ __launch_bounds__(256, 3) void gemm_proj(const short* __restrict__ A,
                                                    const short* __restrict__ Bt,
                                                    const float* __restrict__ bias,
                                                    float* __restrict__ out) {
  const int K = 1024;
  __shared__ short smem[24576];   // 2 x (A 8192 | B 4096)
  int tid = threadIdx.x;
  // XCD swizzle: each XCD owns 2 ntile cols (256 KB B panel, L2-resident)
  int x = blockIdx.x & 7, r = blockIdx.x >> 3;  // r in [0,64)
  int ntile = (x * 2 + (r & 1)) * 64, mtile = (r >> 1) * 128;
  int w = tid >> 6, l = tid & 63;
  int lr = l & 15, lg = l >> 4;

  f32x4 zero4 = {0.f, 0.f, 0.f, 0.f};
  f32x4 acc[2][4];
  #pragma unroll
  for (int i = 0; i < 2; ++i)
    #pragma unroll
    for (int j = 0; j < 4; ++j) acc[i][j] = zero4;

#define STAGE_PRJ(BUF, K0) do {                                                      \
    short* Ab_ = smem + (BUF) * 12288;                                               \
    short* Bb_ = Ab_ + 8192;                                                         \
    _Pragma("unroll")                                                                \
    for (int c = 0; c < 4; ++c) {                                                    \
      int idx = tid + c * 256;                                                       \
      int row = idx >> 3, kc = (idx & 7) ^ (row & 7);                                \
      gl_lds16(&A[(size_t)(mtile + row) * K + (K0) + kc * 8], &Ab_[idx * 8]);        \
    }                                                                                \
    _Pragma("unroll")                                                                \
    for (int c = 0; c < 2; ++c) {                                                    \
      int idx = tid + c * 256;                                                       \
      int row = idx >> 3, kc = (idx & 7) ^ (row & 7);                                \
      gl_lds16(&Bt[(size_t)(ntile + row) * K + (K0) + kc * 8], &Bb_[idx * 8]);       \
    }                                                                                \
  } while (0)

  STAGE_PRJ(0, 0);
  __syncthreads();
  int cur = 0;
  for (int it = 0; it < 16; ++it) {
    if (it < 15) STAGE_PRJ(cur ^ 1, (it + 1) * 64);
    const short* Ab = smem + cur * 12288;
    const short* Bb = Ab + 8192;
    __builtin_amdgcn_s_setprio(1);
    #pragma unroll
    for (int kk = 0; kk < 2; ++kk) {
      bf16x8 af[2], bfr[4];
      #pragma unroll
      for (int i = 0; i < 2; ++i) {
        int rA = w * 32 + i * 16 + lr;
        af[i] = *reinterpret_cast<const bf16x8*>(&Ab[rA * 64 + (((kk * 4 + lg) ^ (rA & 7)) * 8)]);
      }
      #pragma unroll
      for (int j = 0; j < 4; ++j) {
        int rB = j * 16 + lr;
        bfr[j] = *reinterpret_cast<const bf16x8*>(&Bb[rB * 64 + (((kk * 4 + lg) ^ (rB & 7)) * 8)]);
      }
      #pragma unroll
      for (int i = 0; i < 2; ++i)
        #pragma unroll
        for (int j = 0; j < 4; ++j)
          acc[i][j] = __builtin_amdgcn_mfma_f32_16x16x32_bf16(af[i], bfr[j], acc[i][j], 0, 0, 0);
    }
    __builtin_amdgcn_s_setprio(0);
    __syncthreads();
    cur ^= 1;
  }
#undef STAGE_PRJ

  #pragma unroll
  for (int j = 0; j < 4; ++j) {
    int n = ntile + j * 16 + lr;
    float bv = bias[n];
    #pragma unroll
    for (int i = 0; i < 2; ++i) {
      #pragma unroll
      for (int r2 = 0; r2 < 4; ++r2) {
        int m = mtile + w * 32 + i * 16 + lg * 4 + r2;
        out[(size_t)m * 1024 + n] = acc[i][j][r2] + bv;
      }
    }
  }
}

extern "C" void kernel_launch(void* const* d_in, const int* in_sizes, int n_in,
                              void* d_out, int out_size, void* d_ws, size_t ws_size,
                              hipStream_t stream) {
  const float* x     = (const float*)d_in[0];
  const float* Wqkv  = (const float*)d_in[1];
  const float* bqkv  = (const float*)d_in[2];
  const float* Wproj = (const float*)d_in[3];
  const float* bproj = (const float*)d_in[4];
  float* out = (float*)d_out;

  const size_t M4 = 4096ull * 1024ull;
  short* ws = (short*)d_ws;
  short* x_bf    = ws;
  short* wqkv_t  = ws + M4;
  short* wproj_t = ws + M4 + 3ull * 1024 * 1024;
  short* qb      = wproj_t + 1024ull * 1024;
  short* kb      = qb + M4;
  short* vtb     = kb + M4;     // fragment-swizzled V^T
  short* yb      = x_bf;        // alias: x_bf dead after gemm_qkv

  cast_x_kernel<<<4096, 256, 0, stream>>>(x, x_bf, (int)(M4 / 4));
  transpose_cast<<<dim3(48, 16), 256, 0, stream>>>(Wqkv, wqkv_t, 1024, 3072);
  transpose_cast<<<dim3(16, 16), 256, 0, stream>>>(Wproj, wproj_t, 1024, 1024);
  gemm_qkv<<<192, 512, 0, stream>>>(x_bf, wqkv_t, bqkv, qb, kb, vtb);
  attn_kernel<<<1024, 256, 0, stream>>>(qb, kb, vtb, yb);
  gemm_proj<<<512, 256, 0, stream>>>(yb, wproj_t, bproj, out);
}

// Round 28
// 101.596 us; speedup vs baseline: 1.1744x; 1.1043x over previous
//
#include <hip/hip_runtime.h>

// ---- types ----
typedef __bf16 bf16x8 __attribute__((ext_vector_type(8)));
typedef float  f32x4  __attribute__((ext_vector_type(4)));
typedef float  f32x16 __attribute__((ext_vector_type(16)));
typedef unsigned int uint32x4 __attribute__((ext_vector_type(4)));

__device__ __forceinline__ short f2bf(float f) {
  union { float f; unsigned u; } v; v.f = f;
  unsigned r = v.u + 0x7fffu + ((v.u >> 16) & 1u);
  return (short)(r >> 16);
}

// async global->LDS (16B per lane); LDS dest must be wave-uniform base + lane*16
__device__ __forceinline__ void gl_lds16(const short* g, short* l) {
  __builtin_amdgcn_global_load_lds((const __attribute__((address_space(1))) void*)g,
                                   (__attribute__((address_space(3))) void*)l, 16, 0, 0);
}

// ---- fused prep: cast x (blocks 0..4095), transpose Wqkv (4096..4863),
//      transpose Wproj (4864..5119). One launch instead of three. ----
__device__ __forceinline__ void do_transpose(const float* __restrict__ in,
                                             short* __restrict__ out,
                                             int R, int Cc, int bx, int by,
                                             short (*tile)[65]) {
  int tx = threadIdx.x & 63, ty = threadIdx.x >> 6;
  #pragma unroll
  for (int i = ty; i < 64; i += 4)
    tile[i][tx] = f2bf(in[(size_t)(by + i) * Cc + bx + tx]);
  __syncthreads();
  #pragma unroll
  for (int i = ty; i < 64; i += 4)
    out[(size_t)(bx + i) * R + by + tx] = tile[tx][i];
}

__global__ __launch_bounds__(256) void prep_kernel(const float* __restrict__ x,
                                                   short* __restrict__ x_bf,
                                                   const float* __restrict__ Wqkv,
                                                   short* __restrict__ wqkv_t,
                                                   const float* __restrict__ Wproj,
                                                   short* __restrict__ wproj_t) {
  __shared__ short tile[64][65];
  int bid = blockIdx.x;
  if (bid < 4096) {
    int i = bid * 256 + threadIdx.x;
    float4 f = reinterpret_cast<const float4*>(x)[i];
    short4 o;
    o.x = f2bf(f.x); o.y = f2bf(f.y); o.z = f2bf(f.z); o.w = f2bf(f.w);
    reinterpret_cast<short4*>(x_bf)[i] = o;
  } else if (bid < 4864) {
    int idx = bid - 4096;                       // 48 x 16
    do_transpose(Wqkv, wqkv_t, 1024, 3072, (idx % 48) * 64, (idx / 48) * 64, tile);
  } else {
    int idx = bid - 4864;                       // 16 x 16
    do_transpose(Wproj, wproj_t, 1024, 1024, (idx % 16) * 64, (idx / 16) * 64, tile);
  }
}

// ==== swizzled fragment layouts (per bh, 64 tiles x 2048 shorts) ====
// Q/K: (t,d) -> (t>>5)*2048 + (((d>>3)&1)<<10) + (t&31)*32 + ((d>>4)<<3) + (d&7)
// V^T: (d,t) -> (t>>5)*2048 + (((t>>3)&1)<<10) + (d&31)*32
//               + ((((t>>4)&1)+((d>>5)<<1))<<3) + (t&7)

// ---- GEMM1 v8 (r24 best): BM=BN=256, 8 waves, 2-phase dbuf + T2 LDS XOR-swizzle
//      + XCD-chunked mapping ----
__global__ __launch_bounds__(512, 1) void gemm_qkv(const short* __restrict__ A,
                                                   const short* __restrict__ Bt,
                                                   const float* __restrict__ bias,
                                                   short* __restrict__ qo,
                                                   short* __restrict__ ko,
                                                   short* __restrict__ vt) {
  const int K = 1024;
  __shared__ short smem[65536];   // 2 x (A 256x64 | B 256x64); epilogue reuses
  int tid = threadIdx.x;
  int x = blockIdx.x & 7, r = blockIdx.x >> 3;    // 192 blocks: 8 XCD x 24
  int mtile = (x * 2 + (r & 1)) * 256;            // mt in [0,16)
  int ntile = (r >> 1) * 256;                     // nt in [0,12)
  int w = tid >> 6, l = tid & 63;
  int wr = w >> 2, wc = w & 3;     // wave tile: rows [wr*128,+128), cols [wc*64,+64)
  int lr = l & 15, lg = l >> 4;

  f32x4 zero4 = {0.f, 0.f, 0.f, 0.f};
  f32x4 acc[8][4];
  #pragma unroll
  for (int i = 0; i < 8; ++i)
    #pragma unroll
    for (int j = 0; j < 4; ++j) acc[i][j] = zero4;

#define STAGE_QKV(BUF, K0) do {                                                      \
    short* Ab_ = smem + (BUF) * 32768;                                               \
    short* Bb_ = Ab_ + 16384;                                                        \
    _Pragma("unroll")                                                                \
    for (int c = 0; c < 4; ++c) {                                                    \
      int idx = tid + c * 512;                                                       \
      int row = idx >> 3, kc = (idx & 7) ^ (row & 7);   /* pre-swizzled source */    \
      gl_lds16(&A[(size_t)(mtile + row) * K + (K0) + kc * 8], &Ab_[idx * 8]);        \
      gl_lds16(&Bt[(size_t)(ntile + row) * K + (K0) + kc * 8], &Bb_[idx * 8]);       \
    }                                                                                \
  } while (0)

  STAGE_QKV(0, 0);
  __syncthreads();
  int cur = 0;
  for (int it = 0; it < 16; ++it) {
    if (it < 15) STAGE_QKV(cur ^ 1, (it + 1) * 64);   // issue next tile early
    const short* Ab = smem + cur * 32768;
    const short* Bb = Ab + 16384;
    __builtin_amdgcn_s_setprio(1);
    #pragma unroll
    for (int kk = 0; kk < 2; ++kk) {
      bf16x8 af[8], bfr[4];
      #pragma unroll
      for (int i = 0; i < 8; ++i) {
        int rA = wr * 128 + i * 16 + lr;
        af[i] = *reinterpret_cast<const bf16x8*>(&Ab[rA * 64 + (((kk * 4 + lg) ^ (rA & 7)) * 8)]);
      }
      #pragma unroll
      for (int j = 0; j < 4; ++j) {
        int rB = wc * 64 + j * 16 + lr;
        bfr[j] = *reinterpret_cast<const bf16x8*>(&Bb[rB * 64 + (((kk * 4 + lg) ^ (rB & 7)) * 8)]);
      }
      #pragma unroll
      for (int i = 0; i < 8; ++i)
        #pragma unroll
        for (int j = 0; j < 4; ++j)
          acc[i][j] = __builtin_amdgcn_mfma_f32_16x16x32_bf16(af[i], bfr[j], acc[i][j], 0, 0, 0);
    }
    __builtin_amdgcn_s_setprio(0);
    __syncthreads();   // drains this iter's stage AFTER compute
    cur ^= 1;
  }
#undef STAGE_QKV

  // ---- epilogue: bias+scale+cvt -> LDS at final swizzled positions -> coalesced stores
  const int sec = ntile >> 10;   // 0=q 1=k 2=v (uniform: ntile is 256-aligned)
  if (sec == 2) {
    #pragma unroll
    for (int j = 0; j < 4; ++j) {
      int nl = wc * 64 + j * 16 + lr;        // [0,256): spans 4 heads
      int d  = nl & 63;
      float bv = bias[ntile + nl];
      #pragma unroll
      for (int i = 0; i < 8; ++i) {
        int lt0 = wr * 128 + i * 16 + lg * 4; // r spans lt&7 consecutively
        int c2 = (nl >> 6) * 8 + (lt0 >> 5);
        int pos = (((lt0 >> 3) & 1) << 10) + (d & 31) * 32 +
                  ((((lt0 >> 4) & 1) + ((d >> 5) << 1)) << 3) + (lt0 & 7);
        short4 pk;
        pk.x = f2bf(acc[i][j][0] + bv);
        pk.y = f2bf(acc[i][j][1] + bv);
        pk.z = f2bf(acc[i][j][2] + bv);
        pk.w = f2bf(acc[i][j][3] + bv);
        *reinterpret_cast<short4*>(&smem[c2 * 2048 + pos]) = pk;
      }
    }
  } else {
    // q scaled by (1/sqrt(64)) * log2(e) so attention works in exp2 domain
    const float sc = (sec == 0) ? 0.18033688f : 1.0f;
    #pragma unroll
    for (int j = 0; j < 4; ++j) {
      int nl = wc * 64 + j * 16 + lr;
      int d  = nl & 63;
      float bv = bias[ntile + nl];
      int dpart = (((d >> 3) & 1) << 10) + ((d >> 4) << 3) + (d & 7);
      #pragma unroll
      for (int i = 0; i < 8; ++i) {
        #pragma unroll
        for (int r2 = 0; r2 < 4; ++r2) {
          int lt = wr * 128 + i * 16 + lg * 4 + r2;
          int c2 = (nl >> 6) * 8 + (lt >> 5);
          smem[c2 * 2048 + (lt & 31) * 32 + dpart] = f2bf((acc[i][j][r2] + bv) * sc);
        }
      }
    }
  }
  __syncthreads();
  short* dst = (sec == 0) ? qo : ((sec == 1) ? ko : vt);
  int bb  = mtile >> 11;
  int h0  = (ntile & 1023) >> 6;
  int gt0 = (mtile & 2047) >> 5;
  #pragma unroll
  for (int c2 = 0; c2 < 32; ++c2) {
    size_t base = (size_t)(bb * 16 + h0 + (c2 >> 3)) * 131072 +
                  (size_t)(gt0 + (c2 & 7)) * 2048;
    *reinterpret_cast<uint2*>(&dst[base + tid * 4]) =
        *reinterpret_cast<const uint2*>(&smem[c2 * 2048 + tid * 4]);
  }
}

// ---- flash attention v18 (r24 best): paired q-tiles, chain-shortened softmax,
//      C-in=-m init, kv-split + two-pass merge ----
template<int DIAG>
__device__ __forceinline__ void attn_step(const short* __restrict__ kp,
                                          const short* __restrict__ vp,
                                          const bf16x8* qf,
                                          f32x16& y0, f32x16& y1,
                                          float& m, float& li,
                                          int lq, int hl) {
  f32x16 s;
  #pragma unroll
  for (int r = 0; r < 16; ++r) s[r] = -m;
  __builtin_amdgcn_s_setprio(1);
  #pragma unroll
  for (int ks = 0; ks < 4; ++ks) {
    bf16x8 kf = *reinterpret_cast<const bf16x8*>(kp + ks * 8);
    s = __builtin_amdgcn_mfma_f32_32x32x16_bf16(kf, qf[ks], s, 0, 0, 0);
  }
  __builtin_amdgcn_s_setprio(0);
  if (DIAG) {
    #pragma unroll
    for (int r = 0; r < 16; ++r) {
      int kvl = (r & 3) + 8 * (r >> 2) + 4 * hl;
      if (kvl > lq) s[r] = -1e30f;
    }
  }
  float t0 = fmaxf(fmaxf(s[0], s[1]), s[2]);
  float t1 = fmaxf(fmaxf(s[3], s[4]), s[5]);
  float t2 = fmaxf(fmaxf(s[6], s[7]), s[8]);
  float t3 = fmaxf(fmaxf(s[9], s[10]), s[11]);
  float t4 = fmaxf(fmaxf(s[12], s[13]), s[14]);
  float pm = fmaxf(fmaxf(fmaxf(t0, t1), t2), fmaxf(fmaxf(t3, t4), s[15]));
  if (!__all(pm <= 8.0f)) {          // rare: tile max grew past threshold
    float pmu = fmaxf(pm, __shfl_xor(pm, 32));   // row-uniform (shfl only here)
    float delta = fmaxf(pmu, 0.0f);
    float sc = __builtin_amdgcn_exp2f(-delta);
    m += delta;
    li *= sc;
    #pragma unroll
    for (int r = 0; r < 16; ++r) { y0[r] *= sc; y1[r] *= sc; s[r] -= delta; }
  }
  unsigned u[8];
  float rs = 0.f;
  #pragma unroll
  for (int rq = 0; rq < 4; ++rq) {
    float p0 = __builtin_amdgcn_exp2f(s[4 * rq + 0]);
    float p1 = __builtin_amdgcn_exp2f(s[4 * rq + 1]);
    float p2 = __builtin_amdgcn_exp2f(s[4 * rq + 2]);
    float p3 = __builtin_amdgcn_exp2f(s[4 * rq + 3]);
    rs += (p0 + p1) + (p2 + p3);
    asm("v_cvt_pk_bf16_f32 %0, %1, %2" : "=v"(u[rq * 2 + 0]) : "v"(p0), "v"(p1));
    asm("v_cvt_pk_bf16_f32 %0, %1, %2" : "=v"(u[rq * 2 + 1]) : "v"(p2), "v"(p3));
  }
  li += rs;                           // per-lane partial; cross-half sum deferred
  asm volatile("v_permlane32_swap_b32 %0, %1" : "+v"(u[0]), "+v"(u[2]));
  asm volatile("v_permlane32_swap_b32 %0, %1" : "+v"(u[1]), "+v"(u[3]));
  asm volatile("v_permlane32_swap_b32 %0, %1" : "+v"(u[4]), "+v"(u[6]));
  asm volatile("v_permlane32_swap_b32 %0, %1" : "+v"(u[5]), "+v"(u[7]));
  uint32x4 w0 = {u[0], u[1], u[2], u[3]};
  uint32x4 w1 = {u[4], u[5], u[6], u[7]};
  bf16x8 pa0 = __builtin_bit_cast(bf16x8, w0);
  bf16x8 pa1 = __builtin_bit_cast(bf16x8, w1);
  __builtin_amdgcn_s_setprio(1);
  {
    bf16x8 vf00 = *reinterpret_cast<const bf16x8*>(vp);
    bf16x8 vf01 = *reinterpret_cast<const bf16x8*>(vp + 8);
    bf16x8 vf10 = *reinterpret_cast<const bf16x8*>(vp + 16);
    bf16x8 vf11 = *reinterpret_cast<const bf16x8*>(vp + 24);
    y0 = __builtin_amdgcn_mfma_f32_32x32x16_bf16(vf00, pa0, y0, 0, 0, 0);
    y0 = __builtin_amdgcn_mfma_f32_32x32x16_bf16(vf01, pa1, y0, 0, 0, 0);
    y1 = __builtin_amdgcn_mfma_f32_32x32x16_bf16(vf10, pa0, y1, 0, 0, 0);
    y1 = __builtin_amdgcn_mfma_f32_32x32x16_bf16(vf11, pa1, y1, 0, 0, 0);
  }
  __builtin_amdgcn_s_setprio(0);
}

__global__ __launch_bounds__(256, 4) void attn_kernel(const short* __restrict__ q,
                                                      const short* __restrict__ k,
                                                      const short* __restrict__ vt,
                                                      short* __restrict__ y) {
  __shared__ float partL[3][4][64][4];   // 12 KB, reused across passes/halves
  __shared__ float stm[4][32], stl[4][32];
  const int bid = blockIdx.x;            // 1024 blocks: 32 pairs x 32 bh
  const int p = bid >> 5;                // pair index 0..31
  const int b5 = bid & 31;
  const int bh = (b5 & 7) * 4 + (b5 >> 3); // group each bh's blocks on one XCD
  const int tid = threadIdx.x;
  const int w = tid >> 6;                // wave: kv-split index 0..3
  const int l = tid & 63;
  const int lq = l & 31, hl = l >> 5;
  const short* qb = q + (size_t)bh * 131072;
  const short* kb = k + (size_t)bh * 131072;
  const short* vb = vt + (size_t)bh * 131072;
  const int b_ = bh >> 4, h_ = bh & 15;

  #pragma unroll 1
  for (int half = 0; half < 2; ++half) {
    const int t = half ? p : (63 - p);   // q-tile for this pass; total work 65 tiles

    // Q fragments: swizzled -> one coalesced 64B read per lane
    bf16x8 qf[4];
    {
      const short* qp = qb + (size_t)t * 2048 + l * 32;
      #pragma unroll
      for (int ks = 0; ks < 4; ++ks)
        qf[ks] = *reinterpret_cast<const bf16x8*>(qp + ks * 8);
    }

    f32x16 y0, y1;
    #pragma unroll
    for (int r = 0; r < 16; ++r) { y0[r] = 0.f; y1[r] = 0.f; }
    float m = 0.f, li = 0.f;   // m init 0 (defer-max in relative/log2 domain)

    // wave w handles kv tiles {w, w+4, ...} < t, plus diag tile t if t&3==w
    const short* kp = kb + (size_t)w * 2048 + l * 32;
    const short* vp = vb + (size_t)w * 2048 + l * 32;
    for (int it = w; it < t; it += 4) {
      attn_step<0>(kp, vp, qf, y0, y1, m, li, lq, hl);
      kp += 4 * 2048;
      vp += 4 * 2048;
    }
    if ((t & 3) == w) {
      const short* kpd = kb + (size_t)t * 2048 + l * 32;
      const short* vpd = vb + (size_t)t * 2048 + l * 32;
      attn_step<1>(kpd, vpd, qf, y0, y1, m, li, lq, hl);
    }
    // complete the deferred cross-half li sum (per q-row)
    li += __shfl_xor(li, 32);

    // ---- merge the 4 wave-partials (two passes over a half-size buffer) ----
    if (hl == 0) { stm[w][lq] = m; stl[w][lq] = li; }
    __syncthreads();
    float m0 = stm[0][lq], m1 = stm[1][lq], m2 = stm[2][lq], m3 = stm[3][lq];
    float M = fmaxf(fmaxf(m0, m1), fmaxf(m2, m3));
    float L = stl[0][lq] * __builtin_amdgcn_exp2f(m0 - M) +
              stl[1][lq] * __builtin_amdgcn_exp2f(m1 - M) +
              stl[2][lq] * __builtin_amdgcn_exp2f(m2 - M) +
              stl[3][lq] * __builtin_amdgcn_exp2f(m3 - M);
    float sc = __builtin_amdgcn_exp2f(m - M);
    #pragma unroll
    for (int r = 0; r < 16; ++r) { y0[r] *= sc; y1[r] *= sc; }

    // pass 0: merge y0
    if (w > 0) {
      #pragma unroll
      for (int c = 0; c < 4; ++c) {
        f32x4 v0s = {y0[4 * c + 0], y0[4 * c + 1], y0[4 * c + 2], y0[4 * c + 3]};
        *reinterpret_cast<f32x4*>(&partL[w - 1][c][l][0]) = v0s;
      }
    }
    __syncthreads();
    if (w == 0) {
      #pragma unroll
      for (int o = 0; o < 3; ++o)
        #pragma unroll
        for (int c = 0; c < 4; ++c) {
          f32x4 v0s = *reinterpret_cast<const f32x4*>(&partL[o][c][l][0]);
          #pragma unroll
          for (int r = 0; r < 4; ++r) y0[4 * c + r] += v0s[r];
        }
    }
    __syncthreads();
    // pass 1: merge y1 (buffer reused)
    if (w > 0) {
      #pragma unroll
      for (int c = 0; c < 4; ++c) {
        f32x4 v1s = {y1[4 * c + 0], y1[4 * c + 1], y1[4 * c + 2], y1[4 * c + 3]};
        *reinterpret_cast<f32x4*>(&partL[w - 1][c][l][0]) = v1s;
      }
    }
    __syncthreads();
    if (w == 0) {
      #pragma unroll
      for (int o = 0; o < 3; ++o)
        #pragma unroll
        for (int c = 0; c < 4; ++c) {
          f32x4 v1s = *reinterpret_cast<const f32x4*>(&partL[o][c][l][0]);
          #pragma unroll
          for (int r = 0; r < 4; ++r) y1[4 * c + r] += v1s[r];
        }
      float inv = 1.0f / L;
      short* yrow = &y[(size_t)(b_ * 2048 + 32 * t + lq) * 1024 + h_ * 64];
      #pragma unroll
      for (int dt = 0; dt < 2; ++dt) {
        const f32x16& yy = dt ? y1 : y0;
        #pragma unroll
        for (int rq = 0; rq < 4; ++rq) {
          int d0 = dt * 32 + 8 * rq + 4 * hl;
          uint2 pk;
          pk.x = (unsigned)(unsigned short)f2bf(yy[4 * rq + 0] * inv) |
                 ((unsigned)(unsigned short)f2bf(yy[4 * rq + 1] * inv) << 16);
          pk.y = (unsigned)(unsigned short)f2bf(yy[4 * rq + 2] * inv) |
                 ((unsigned)(unsigned short)f2bf(yy[4 * rq + 3] * inv) << 16);
          *reinterpret_cast<uint2*>(yrow + d0) = pk;
        }
      }
    }
    __syncthreads();   // protect stm/partL reuse by next half
  }
}

// ---- GEMM3 v5: BM=128 x BN=64, 2-phase dbuf + XCD swizzle + T2 LDS swizzle ----
__global__ __launch_bounds__(256, 3) void gemm_proj(const short* __restrict__ A,
                                                    const short* __restrict__ Bt,
                                                    const float* __restrict__ bias,
                                                    float* __restrict__ out) {
  const int K = 1024;
  __shared__ short smem[24576];   // 2 x (A 8192 | B 4096)
  int tid = threadIdx.x;
  // XCD swizzle: each XCD owns 2 ntile cols (256 KB B panel, L2-resident)
  int x = blockIdx.x & 7, r = blockIdx.x >> 3;  // r in [0,64)
  int ntile = (x * 2 + (r & 1)) * 64, mtile = (r >> 1) * 128;
  int w = tid >> 6, l = tid & 63;
  int lr = l & 15, lg = l >> 4;

  f32x4 zero4 = {0.f, 0.f, 0.f, 0.f};
  f32x4 acc[2][4];
  #pragma unroll
  for (int i = 0; i < 2; ++i)
    #pragma unroll
    for (int j = 0; j < 4; ++j) acc[i][j] = zero4;

#define STAGE_PRJ(BUF, K0) do {                                                      \
    short* Ab_ = smem + (BUF) * 12288;                                               \
    short* Bb_ = Ab_ + 8192;                                                         \
    _Pragma("unroll")                                                                \
    for (int c = 0; c < 4; ++c) {                                                    \
      int idx = tid + c * 256;                                                       \
      int row = idx >> 3, kc = (idx & 7) ^ (row & 7);                                \
      gl_lds16(&A[(size_t)(mtile + row) * K + (K0) + kc * 8], &Ab_[idx * 8]);        \
    }                                                                                \
    _Pragma("unroll")                                                                \
    for (int c = 0; c < 2; ++c) {                                                    \
      int idx = tid + c * 256;                                                       \
      int row = idx >> 3, kc = (idx & 7) ^ (row & 7);                                \
      gl_lds16(&Bt[(size_t)(ntile + row) * K + (K0) + kc * 8], &Bb_[idx * 8]);       \
    }                                                                                \
  } while (0)

  STAGE_PRJ(0, 0);
  __syncthreads();
  int cur = 0;
  for (int it = 0; it < 16; ++it) {
    if (it < 15) STAGE_PRJ(cur ^ 1, (it + 1) * 64);
    const short* Ab = smem + cur * 12288;
    const short* Bb = Ab + 8192;
    __builtin_amdgcn_s_setprio(1);
    #pragma unroll
    for (int kk = 0; kk < 2; ++kk) {
      bf16x8 af[2], bfr[4];
      #pragma unroll
      for (int i = 0; i < 2; ++i) {
        int rA = w * 32 + i * 16 + lr;
        af[i] = *reinterpret_cast<const bf16x8*>(&Ab[rA * 64 + (((kk * 4 + lg) ^ (rA & 7)) * 8)]);
      }
      #pragma unroll
      for (int j = 0; j < 4; ++j) {
        int rB = j * 16 + lr;
        bfr[j] = *reinterpret_cast<const bf16x8*>(&Bb[rB * 64 + (((kk * 4 + lg) ^ (rB & 7)) * 8)]);
      }
      #pragma unroll
      for (int i = 0; i < 2; ++i)
        #pragma unroll
        for (int j = 0; j < 4; ++j)
          acc[i][j] = __builtin_amdgcn_mfma_f32_16x16x32_bf16(af[i], bfr[j], acc[i][j], 0, 0, 0);
    }
    __builtin_amdgcn_s_setprio(0);
    __syncthreads();
    cur ^= 1;
  }
#undef STAGE_PRJ

  #pragma unroll
  for (int j = 0; j < 4; ++j) {
    int n = ntile + j * 16 + lr;
    float bv = bias[n];
    #pragma unroll
    for (int i = 0; i < 2; ++i) {
      #pragma unroll
      for (int r2 = 0; r2 < 4; ++r2) {
        int m = mtile + w * 32 + i * 16 + lg * 4 + r2;
        out[(size_t)m * 1024 + n] = acc[i][j][r2] + bv;
      }
    }
  }
}

extern "C" void kernel_launch(void* const* d_in, const int* in_sizes, int n_in,
                              void* d_out, int out_size, void* d_ws, size_t ws_size,
                              hipStream_t stream) {
  const float* x     = (const float*)d_in[0];
  const float* Wqkv  = (const float*)d_in[1];
  const float* bqkv  = (const float*)d_in[2];
  const float* Wproj = (const float*)d_in[3];
  const float* bproj = (const float*)d_in[4];
  float* out = (float*)d_out;

  const size_t M4 = 4096ull * 1024ull;
  short* ws = (short*)d_ws;
  short* x_bf    = ws;
  short* wqkv_t  = ws + M4;
  short* wproj_t = ws + M4 + 3ull * 1024 * 1024;
  short* qb      = wproj_t + 1024ull * 1024;
  short* kb      = qb + M4;
  short* vtb     = kb + M4;     // fragment-swizzled V^T
  short* yb      = x_bf;        // alias: x_bf dead after gemm_qkv

  prep_kernel<<<5120, 256, 0, stream>>>(x, x_bf, Wqkv, wqkv_t, Wproj, wproj_t);
  gemm_qkv<<<192, 512, 0, stream>>>(x_bf, wqkv_t, bqkv, qb, kb, vtb);
  attn_kernel<<<1024, 256, 0, stream>>>(qb, kb, vtb, yb);
  gemm_proj<<<512, 256, 0, stream>>>(yb, wproj_t, bproj, out);
}